// Round 1
// baseline (307.460 us; speedup 1.0000x reference)
//
#include <hip/hip_runtime.h>
#include <stdint.h>

typedef __bf16 bf16;
typedef __bf16 bf16x8 __attribute__((ext_vector_type(8)));
typedef float f32x4 __attribute__((ext_vector_type(4)));

// ---------------------------------------------------------------- cast x->bf16
__global__ __launch_bounds__(256) void k_cast(const float* __restrict__ src,
                                              bf16* __restrict__ dst, int n8) {
  int i = blockIdx.x * 256 + threadIdx.x;
  if (i >= n8) return;
  const float4* s = reinterpret_cast<const float4*>(src) + (size_t)i * 2;
  float4 a = s[0], b = s[1];
  bf16x8 o;
  o[0] = (bf16)a.x; o[1] = (bf16)a.y; o[2] = (bf16)a.z; o[3] = (bf16)a.w;
  o[4] = (bf16)b.x; o[5] = (bf16)b.y; o[6] = (bf16)b.z; o[7] = (bf16)b.w;
  *reinterpret_cast<bf16x8*>(dst + (size_t)i * 8) = o;
}

// ------------------------------------------------------- transpose + cast bf16
// src [R][C] f32 row-major -> dst [C][R] bf16 row-major. 64x64 tiles.
struct TP4 { const float* src[4]; bf16* dst[4]; };

__global__ __launch_bounds__(256) void k_tcast(TP4 args, int R, int C) {
  const float* __restrict__ src = args.src[blockIdx.z];
  bf16* __restrict__ dst = args.dst[blockIdx.z];
  __shared__ float tile[64][65];
  const int r0 = blockIdx.y * 64, c0 = blockIdx.x * 64;
  const int tr = threadIdx.x >> 6, tc = threadIdx.x & 63;
#pragma unroll
  for (int i = 0; i < 16; ++i) {
    int r = i * 4 + tr;
    tile[r][tc] = src[(size_t)(r0 + r) * C + (c0 + tc)];
  }
  __syncthreads();
#pragma unroll
  for (int i = 0; i < 16; ++i) {
    int r = i * 4 + tr;
    dst[(size_t)(c0 + r) * R + (r0 + tc)] = (bf16)tile[tc][r];
  }
}

// ---------------------------------------------------------------- NT bf16 GEMM
// C[m][n] = sum_k A[m][k] * Bt[n][k].  128x128 tile, BK=32, 4 waves (2x2),
// each wave 64x64 (4x4 frags of 16x16x32 MFMA).  global_load_lds width 16
// with pre-swizzled global source; XOR-swizzled ds_read_b128 (2-way max).
#define GLL(gp, lp)                                              \
  __builtin_amdgcn_global_load_lds(                              \
      (const __attribute__((address_space(1))) void*)(gp),       \
      (__attribute__((address_space(3))) void*)(lp), 16, 0, 0)

template <typename CT>
__global__ __launch_bounds__(256) void k_gemm_nt(
    const bf16* __restrict__ A, const bf16* __restrict__ Bt, CT* __restrict__ C,
    int lda, int ldb, int ldc, int Kd, long sA, long sB, long sC) {
  A += (long)blockIdx.z * sA;
  Bt += (long)blockIdx.z * sB;
  C += (long)blockIdx.z * sC;
  const int mb = blockIdx.x, nb = blockIdx.y;
  __shared__ bf16 As[2][128 * 32];
  __shared__ bf16 Bs[2][128 * 32];
  const int tid = threadIdx.x, lane = tid & 63, wid = tid >> 6;
  const int wr = wid >> 1, wc = wid & 1;
  // staging geometry: chunk = 1KB = 16 rows x 32k; lane -> row chunk*16+(lane>>2),
  // physical slot lane&3 holds logical k-slot (lane&3)^(row&3)  (XOR involution)
  const int srow = lane >> 2;
  const int skk = (((lane & 3) ^ (srow & 3)) << 3);

  f32x4 acc[4][4] = {};
  const bf16* Abase = A + (long)mb * 128 * lda;
  const bf16* Bbase = Bt + (long)nb * 128 * ldb;

  auto stage = [&](int buf, int k0) {
#pragma unroll
    for (int i = 0; i < 2; ++i) {
      const int ch = wid * 2 + i;
      const int row = ch * 16 + srow;
      GLL(Abase + (long)row * lda + k0 + skk, &As[buf][ch * 512]);
      GLL(Bbase + (long)row * ldb + k0 + skk, &Bs[buf][ch * 512]);
    }
  };

  stage(0, 0);
  const int nk = Kd >> 5;
  for (int kt = 0; kt < nk; ++kt) {
    const int cur = kt & 1;
    if (kt + 1 < nk) stage(cur ^ 1, (kt + 1) << 5);
    __syncthreads();
    const int slot = lane >> 4;  // k0 = slot*8
    bf16x8 af[4], bb[4];
#pragma unroll
    for (int i = 0; i < 4; ++i) {
      const int r = wr * 64 + i * 16 + (lane & 15);
      af[i] = *reinterpret_cast<const bf16x8*>(
          reinterpret_cast<const char*>(As[cur]) + r * 64 + ((slot ^ (r & 3)) << 4));
      const int c = wc * 64 + i * 16 + (lane & 15);
      bb[i] = *reinterpret_cast<const bf16x8*>(
          reinterpret_cast<const char*>(Bs[cur]) + c * 64 + ((slot ^ (c & 3)) << 4));
    }
#pragma unroll
    for (int i = 0; i < 4; ++i)
#pragma unroll
      for (int j = 0; j < 4; ++j)
        acc[i][j] =
            __builtin_amdgcn_mfma_f32_16x16x32_bf16(af[i], bb[j], acc[i][j], 0, 0, 0);
    __syncthreads();
  }

  // epilogue: D layout col=lane&15, row=(lane>>4)*4+r
  const long row0 = (long)mb * 128 + wr * 64 + ((lane >> 4) << 2);
  const int col0 = nb * 128 + wc * 64 + (lane & 15);
#pragma unroll
  for (int i = 0; i < 4; ++i)
#pragma unroll
    for (int j = 0; j < 4; ++j)
#pragma unroll
      for (int r = 0; r < 4; ++r)
        C[(row0 + i * 16 + r) * ldc + (col0 + j * 16)] = (CT)acc[i][j][r];
}

// ------------------------------------------------------------- fused attention
// grid (64 l-tiles, 16 heads, 4 batch), 256 thr (4 waves x 16 Q-rows).
// K=256 compressed keys. LDS 64KB: [0,32KB) Ks (later reused as per-wave Ps),
// [32KB,64KB) Vs = V^T (hash-swizzled).
__global__ __launch_bounds__(256) void k_attn(const bf16* __restrict__ q,
                                              const bf16* __restrict__ kvc,
                                              bf16* __restrict__ aout) {
  const int lt = blockIdx.x, h = blockIdx.y, b = blockIdx.z;
  const int tid = threadIdx.x, lane = tid & 63, wid = tid >> 6;
  __shared__ bf16 smem[32768];  // 64 KB
  bf16* Ks = smem;              // [256][64], swizzled, 32 KB
  bf16* Vs = smem + 16384;      // [64][256] = V^T, swizzled, 32 KB
  bf16* Ps = smem + wid * 4096; // per-wave [16][256], overlaps Ks after barrier

  const bf16* kb = kvc + ((long)b * 512) * 1024 + h * 64;
  const bf16* vb = kb + 256 * 1024;
#pragma unroll
  for (int it = 0; it < 8; ++it) {
    const int kk = it * 32 + (tid >> 3);
    const int dd = (tid & 7) * 8;
    bf16x8 kv = *reinterpret_cast<const bf16x8*>(kb + (long)kk * 1024 + dd);
    *reinterpret_cast<bf16x8*>(reinterpret_cast<char*>(Ks) + kk * 128 +
                               ((((dd >> 3) ^ (kk & 7))) << 4)) = kv;
    bf16x8 vv = *reinterpret_cast<const bf16x8*>(vb + (long)kk * 1024 + dd);
#pragma unroll
    for (int j = 0; j < 8; ++j) {
      const int d = dd + j;
      const int swz = (((d & 7) ^ ((d >> 3) & 7)) << 4);
      *reinterpret_cast<bf16*>(reinterpret_cast<char*>(Vs) + d * 512 +
                               ((kk * 2) ^ swz)) = vv[j];
    }
  }

  // Q fragments straight from global: row = lane&15 of this wave's 16 rows
  const bf16* qb =
      q + ((long)(b * 4096 + lt * 64 + wid * 16 + (lane & 15))) * 1024 + h * 64;
  bf16x8 qf[2];
#pragma unroll
  for (int ks = 0; ks < 2; ++ks)
    qf[ks] = *reinterpret_cast<const bf16x8*>(qb + ks * 32 + ((lane >> 4) << 3));

  __syncthreads();

  // QK^T: logits [16 rows][256]
  f32x4 ln[16] = {};
#pragma unroll
  for (int ks = 0; ks < 2; ++ks) {
    const int slot = ks * 4 + (lane >> 4);  // k0 = slot*8 within head-dim 64
#pragma unroll
    for (int nf = 0; nf < 16; ++nf) {
      const int kcol = nf * 16 + (lane & 15);
      bf16x8 kf = *reinterpret_cast<const bf16x8*>(
          reinterpret_cast<const char*>(Ks) + kcol * 128 + ((slot ^ (kcol & 7)) << 4));
      ln[nf] = __builtin_amdgcn_mfma_f32_16x16x32_bf16(qf[ks], kf, ln[nf], 0, 0, 0);
    }
  }

  __syncthreads();  // all waves done reading Ks; Ps may now clobber it

  // softmax (scale 1/8) per row; lane holds rows (lane>>4)*4+r, cols lane&15+16*nf
#pragma unroll
  for (int r = 0; r < 4; ++r) {
    float m = -1e30f;
#pragma unroll
    for (int nf = 0; nf < 16; ++nf) m = fmaxf(m, ln[nf][r]);
#pragma unroll
    for (int s = 1; s < 16; s <<= 1) m = fmaxf(m, __shfl_xor(m, s, 64));
    float sum = 0.f;
#pragma unroll
    for (int nf = 0; nf < 16; ++nf) {
      float p = __expf((ln[nf][r] - m) * 0.125f);
      ln[nf][r] = p;
      sum += p;
    }
#pragma unroll
    for (int s = 1; s < 16; s <<= 1) sum += __shfl_xor(sum, s, 64);
    const float inv = 1.f / sum;
    const int row = ((lane >> 4) << 2) + r;
#pragma unroll
    for (int nf = 0; nf < 16; ++nf) {
      const int col = nf * 16 + (lane & 15);
      *reinterpret_cast<bf16*>(reinterpret_cast<char*>(Ps) + row * 512 +
                               ((col * 2) ^ ((row & 7) << 4))) = (bf16)(ln[nf][r] * inv);
    }
  }

  // PV: out[16][64] = P[16][256] @ V[256][64]
  f32x4 oacc[4] = {};
#pragma unroll
  for (int ks = 0; ks < 8; ++ks) {
    const int ak = ks * 32 + ((lane >> 4) << 3);
    const int arow = lane & 15;
    bf16x8 pa = *reinterpret_cast<const bf16x8*>(
        reinterpret_cast<const char*>(Ps) + arow * 512 + ((ak * 2) ^ ((arow & 7) << 4)));
#pragma unroll
    for (int nf = 0; nf < 4; ++nf) {
      const int d2 = nf * 16 + (lane & 15);
      const int swz = (((d2 & 7) ^ ((d2 >> 3) & 7)) << 4);
      bf16x8 vv = *reinterpret_cast<const bf16x8*>(
          reinterpret_cast<const char*>(Vs) + d2 * 512 + ((ak * 2) ^ swz));
      oacc[nf] = __builtin_amdgcn_mfma_f32_16x16x32_bf16(pa, vv, oacc[nf], 0, 0, 0);
    }
  }

  bf16* ob = aout + ((long)(b * 4096 + lt * 64 + wid * 16 + ((lane >> 4) << 2))) * 1024 +
             h * 64 + (lane & 15);
#pragma unroll
  for (int nf = 0; nf < 4; ++nf)
#pragma unroll
    for (int r = 0; r < 4; ++r) ob[(long)r * 1024 + nf * 16] = (bf16)oacc[nf][r];
}

// --------------------------------------------------------------------- launch
extern "C" void kernel_launch(void* const* d_in, const int* in_sizes, int n_in,
                              void* d_out, int out_size, void* d_ws, size_t ws_size,
                              hipStream_t stream) {
  const float* x  = (const float*)d_in[0];
  const float* Wq = (const float*)d_in[1];
  const float* Wk = (const float*)d_in[2];
  const float* Wv = (const float*)d_in[3];
  const float* Wo = (const float*)d_in[4];
  const float* Pk = (const float*)d_in[5];
  const float* Pv = (const float*)d_in[6];
  char* ws = (char*)d_ws;
  const long MB = 1024L * 1024;
  bf16* xbf = (bf16*)ws;               // 32 MB  (dead after Q gemm -> reused as aout)
  bf16* XT  = (bf16*)(ws + 32 * MB);   // 32 MB  x^T per batch [1024][4096]
  bf16* WqT = (bf16*)(ws + 64 * MB);   // 2 MB
  bf16* WkT = (bf16*)(ws + 66 * MB);
  bf16* WvT = (bf16*)(ws + 68 * MB);
  bf16* WoT = (bf16*)(ws + 70 * MB);
  bf16* PT  = (bf16*)(ws + 72 * MB);   // 4 MB  [Pk^T ; Pv^T] = [512][4096]
  bf16* qbf = (bf16*)(ws + 76 * MB);   // 32 MB
  bf16* XC  = (bf16*)(ws + 108 * MB);  // 4 MB  [4][512][1024]
  bf16* kvc = (bf16*)(ws + 112 * MB);  // 4 MB  [4][ kc(256) ; vc(256) ][1024]
  bf16* aout = xbf;
  (void)in_sizes; (void)n_in; (void)out_size; (void)ws_size;

  // 1) x -> bf16
  k_cast<<<dim3(8192), 256, 0, stream>>>(x, xbf, (16384 * 1024) / 8);

  // 2) W transposes (bf16)
  TP4 tw = {{Wq, Wk, Wv, Wo}, {WqT, WkT, WvT, WoT}};
  k_tcast<<<dim3(16, 16, 4), 256, 0, stream>>>(tw, 1024, 1024);

  // 3) P transposes into PT cat
  TP4 tp = {{Pk, Pv, Pk, Pk}, {PT, PT + 256 * 4096, PT, PT}};
  k_tcast<<<dim3(4, 64, 2), 256, 0, stream>>>(tp, 4096, 256);

  // 4) x^T per batch
  TP4 tx = {{x, x + 4096 * 1024, x + 2L * 4096 * 1024, x + 3L * 4096 * 1024},
            {XT, XT + 1024L * 4096, XT + 2L * 1024 * 4096, XT + 3L * 1024 * 4096}};
  k_tcast<<<dim3(16, 64, 4), 256, 0, stream>>>(tx, 4096, 1024);

  // 5) Q = x @ Wq        [16384,1024]
  k_gemm_nt<bf16><<<dim3(128, 8, 1), 256, 0, stream>>>(xbf, WqT, qbf, 1024, 1024, 1024,
                                                       1024, 0, 0, 0);
  // 6) XC[b] = [Pk^T;Pv^T] @ x[b]   M=512,N=1024,K=4096
  k_gemm_nt<bf16><<<dim3(4, 8, 4), 256, 0, stream>>>(PT, XT, XC, 4096, 4096, 1024, 4096,
                                                     0, 1024L * 4096, 512L * 1024);
  // 7) kc[b] = XCk[b] @ Wk   M=256
  k_gemm_nt<bf16><<<dim3(2, 8, 4), 256, 0, stream>>>(XC, WkT, kvc, 1024, 1024, 1024,
                                                     1024, 512L * 1024, 0, 512L * 1024);
  // 8) vc[b] = XCv[b] @ Wv
  k_gemm_nt<bf16><<<dim3(2, 8, 4), 256, 0, stream>>>(XC + 256 * 1024, WvT,
                                                     kvc + 256 * 1024, 1024, 1024, 1024,
                                                     1024, 512L * 1024, 0, 512L * 1024);
  // 9) attention
  k_attn<<<dim3(64, 16, 4), 256, 0, stream>>>(qbf, kvc, aout);

  // 10) out = aout @ Wo  (fp32 out)
  k_gemm_nt<float><<<dim3(128, 8, 1), 256, 0, stream>>>(aout, WoT, (float*)d_out, 1024,
                                                        1024, 1024, 1024, 0, 0, 0);
}

// Round 2
// 239.221 us; speedup vs baseline: 1.2853x; 1.2853x over previous
//
#include <hip/hip_runtime.h>
#include <stdint.h>

typedef __bf16 bf16;
typedef __bf16 bf16x4 __attribute__((ext_vector_type(4)));
typedef __bf16 bf16x8 __attribute__((ext_vector_type(8)));
typedef float f32x4 __attribute__((ext_vector_type(4)));

// --------------------------------------------- fused cast + transpose for x
// per batch z: src [4096][1024] f32 -> dst [4096][1024] bf16 AND dstT [1024][4096] bf16
__global__ __launch_bounds__(256) void k_castT(const float* __restrict__ src,
                                               bf16* __restrict__ dst,
                                               bf16* __restrict__ dstT) {
  const size_t bo = (size_t)blockIdx.z * 4096 * 1024;
  const float* s = src + bo;
  bf16* d = dst + bo;
  bf16* dT = dstT + bo;
  __shared__ float tile[64][65];
  const int r0 = blockIdx.y * 64, c0 = blockIdx.x * 64;
  const int tr = threadIdx.x >> 6, tc = threadIdx.x & 63;
#pragma unroll
  for (int i = 0; i < 16; ++i) {
    const int r = i * 4 + tr;
    const float v = s[(size_t)(r0 + r) * 1024 + (c0 + tc)];
    tile[r][tc] = v;
    d[(size_t)(r0 + r) * 1024 + (c0 + tc)] = (bf16)v;
  }
  __syncthreads();
#pragma unroll
  for (int i = 0; i < 16; ++i) {
    const int r = i * 4 + tr;
    dT[(size_t)(c0 + r) * 4096 + (r0 + tc)] = (bf16)tile[tc][r];
  }
}

// ------------------------------------------------------- transpose + cast bf16
// src [R][C] f32 row-major -> dst [C][R] bf16 row-major. 64x64 tiles.
struct TP4 { const float* src[4]; bf16* dst[4]; };

__global__ __launch_bounds__(256) void k_tcast(TP4 args, int R, int C) {
  const float* __restrict__ src = args.src[blockIdx.z];
  bf16* __restrict__ dst = args.dst[blockIdx.z];
  __shared__ float tile[64][65];
  const int r0 = blockIdx.y * 64, c0 = blockIdx.x * 64;
  const int tr = threadIdx.x >> 6, tc = threadIdx.x & 63;
#pragma unroll
  for (int i = 0; i < 16; ++i) {
    int r = i * 4 + tr;
    tile[r][tc] = src[(size_t)(r0 + r) * C + (c0 + tc)];
  }
  __syncthreads();
#pragma unroll
  for (int i = 0; i < 16; ++i) {
    int r = i * 4 + tr;
    dst[(size_t)(c0 + r) * R + (r0 + tc)] = (bf16)tile[tc][r];
  }
}

// ---------------------------------------------------------------- NT bf16 GEMM
// C[m][n] = sum_k A[m][k] * Bt[n][k].  128x128 tile, BK=32, 4 waves (2x2),
// each wave 64x64 (4x4 frags of 16x16x32 MFMA).  global_load_lds width 16
// with pre-swizzled global source; XOR-swizzled ds_read_b128.
// Swizzle f(r) = (r>>1)&3: bank position (r&1)*4 + (slot^f(r)) covers all 8
// 16B-positions per 128B exactly twice over 16 rows -> 2-way only (free).
// zmod/kOff: split-K (z = batch*zmod + kchunk); mbSplit: block-diag B select.
#define GLL(gp, lp)                                              \
  __builtin_amdgcn_global_load_lds(                              \
      (const __attribute__((address_space(1))) void*)(gp),       \
      (__attribute__((address_space(3))) void*)(lp), 16, 0, 0)

template <typename CT>
__global__ __launch_bounds__(256) void k_gemm_nt(
    const bf16* __restrict__ A, const bf16* __restrict__ Bt,
    const bf16* __restrict__ Bt2, CT* __restrict__ C,
    int lda, int ldb, int ldc, int Kd, long sA, long sB, long sC,
    int zmod, long kOff, int mbSplit) {
  int zb = blockIdx.z, kc = 0;
  if (zmod > 1) { zb = blockIdx.z / zmod; kc = blockIdx.z % zmod; }
  const int mb = blockIdx.x, nb = blockIdx.y;
  A += (long)zb * sA + (long)kc * kOff;
  const bf16* Bsel = (mb < mbSplit) ? Bt : Bt2;
  Bsel += (long)zb * sB + (long)kc * kOff;
  C += (long)blockIdx.z * sC;

  __shared__ bf16 As[2][128 * 32];
  __shared__ bf16 Bs[2][128 * 32];
  const int tid = threadIdx.x, lane = tid & 63, wid = tid >> 6;
  const int wr = wid >> 1, wc = wid & 1;
  // staging: chunk = 1KB = 16 rows x 32k; lane -> row chunk*16+(lane>>2);
  // physical 16B slot (lane&3) holds logical k-slot (lane&3)^((srow>>1)&3)
  const int srow = lane >> 2;
  const int skk = (((lane & 3) ^ ((srow >> 1) & 3)) << 3);

  f32x4 acc[4][4] = {};
  const bf16* Abase = A + (long)mb * 128 * lda;
  const bf16* Bbase = Bsel + (long)nb * 128 * ldb;

  auto stage = [&](int buf, int k0) {
#pragma unroll
    for (int i = 0; i < 2; ++i) {
      const int ch = wid * 2 + i;
      const int row = ch * 16 + srow;
      GLL(Abase + (long)row * lda + k0 + skk, &As[buf][ch * 512]);
      GLL(Bbase + (long)row * ldb + k0 + skk, &Bs[buf][ch * 512]);
    }
  };

  stage(0, 0);
  const int nk = Kd >> 5;
  for (int kt = 0; kt < nk; ++kt) {
    const int cur = kt & 1;
    if (kt + 1 < nk) stage(cur ^ 1, (kt + 1) << 5);
    __syncthreads();
    const int slot = lane >> 4;  // logical k0 = slot*8
    bf16x8 af[4], bb[4];
#pragma unroll
    for (int i = 0; i < 4; ++i) {
      const int r = wr * 64 + i * 16 + (lane & 15);
      af[i] = *reinterpret_cast<const bf16x8*>(
          reinterpret_cast<const char*>(As[cur]) + r * 64 +
          ((slot ^ ((r >> 1) & 3)) << 4));
      const int c = wc * 64 + i * 16 + (lane & 15);
      bb[i] = *reinterpret_cast<const bf16x8*>(
          reinterpret_cast<const char*>(Bs[cur]) + c * 64 +
          ((slot ^ ((c >> 1) & 3)) << 4));
    }
#pragma unroll
    for (int i = 0; i < 4; ++i)
#pragma unroll
      for (int j = 0; j < 4; ++j)
        acc[i][j] =
            __builtin_amdgcn_mfma_f32_16x16x32_bf16(af[i], bb[j], acc[i][j], 0, 0, 0);
    __syncthreads();
  }

  // epilogue: D layout col=lane&15, row=(lane>>4)*4+r
  const long row0 = (long)mb * 128 + wr * 64 + ((lane >> 4) << 2);
  const int col0 = nb * 128 + wc * 64 + (lane & 15);
#pragma unroll
  for (int i = 0; i < 4; ++i)
#pragma unroll
    for (int j = 0; j < 4; ++j)
#pragma unroll
      for (int r = 0; r < 4; ++r)
        C[(row0 + i * 16 + r) * ldc + (col0 + j * 16)] = (CT)acc[i][j][r];
}

// ---------------------------------------------- split-K partial reduce (4 -> 1)
// p: [16][512*1024] f32 with slab z = b*4 + kc;  out: [4][512*1024] bf16
__global__ __launch_bounds__(256) void k_red4(const float* __restrict__ p,
                                              bf16* __restrict__ out) {
  const int i = blockIdx.x * 256 + threadIdx.x;  // [0, 524288)
  const int SL = 512 * 1024;
  const int b = (i * 4) / SL;
  const int e = (i * 4) % SL;
  const float* base = p + (size_t)b * 4 * SL + e;
  float4 s0 = *reinterpret_cast<const float4*>(base);
  float4 s1 = *reinterpret_cast<const float4*>(base + SL);
  float4 s2 = *reinterpret_cast<const float4*>(base + 2 * SL);
  float4 s3 = *reinterpret_cast<const float4*>(base + 3 * SL);
  bf16x4 o;
  o[0] = (bf16)(s0.x + s1.x + s2.x + s3.x);
  o[1] = (bf16)(s0.y + s1.y + s2.y + s3.y);
  o[2] = (bf16)(s0.z + s1.z + s2.z + s3.z);
  o[3] = (bf16)(s0.w + s1.w + s2.w + s3.w);
  *reinterpret_cast<bf16x4*>(out + (size_t)b * SL + e) = o;
}

// ------------------------------------------------------------- fused attention
// grid (64 l-tiles, 16 heads, 4 batch), 256 thr (4 waves x 16 Q-rows).
__global__ __launch_bounds__(256) void k_attn(const bf16* __restrict__ q,
                                              const bf16* __restrict__ kvc,
                                              bf16* __restrict__ aout) {
  const int lt = blockIdx.x, h = blockIdx.y, b = blockIdx.z;
  const int tid = threadIdx.x, lane = tid & 63, wid = tid >> 6;
  __shared__ bf16 smem[32768];  // 64 KB
  bf16* Ks = smem;              // [256][64], swizzled, 32 KB
  bf16* Vs = smem + 16384;      // [64][256] = V^T, swizzled, 32 KB
  bf16* Ps = smem + wid * 4096; // per-wave [16][256], overlaps Ks after barrier

  const bf16* kb = kvc + ((long)b * 512) * 1024 + h * 64;
  const bf16* vb = kb + 256 * 1024;
#pragma unroll
  for (int it = 0; it < 8; ++it) {
    const int kk = it * 32 + (tid >> 3);
    const int dd = (tid & 7) * 8;
    bf16x8 kv = *reinterpret_cast<const bf16x8*>(kb + (long)kk * 1024 + dd);
    *reinterpret_cast<bf16x8*>(reinterpret_cast<char*>(Ks) + kk * 128 +
                               ((((dd >> 3) ^ (kk & 7))) << 4)) = kv;
    bf16x8 vv = *reinterpret_cast<const bf16x8*>(vb + (long)kk * 1024 + dd);
#pragma unroll
    for (int j = 0; j < 8; ++j) {
      const int d = dd + j;
      const int swz = (((d & 7) ^ ((d >> 3) & 7)) << 4);
      *reinterpret_cast<bf16*>(reinterpret_cast<char*>(Vs) + d * 512 +
                               ((kk * 2) ^ swz)) = vv[j];
    }
  }

  const bf16* qb =
      q + ((long)(b * 4096 + lt * 64 + wid * 16 + (lane & 15))) * 1024 + h * 64;
  bf16x8 qf[2];
#pragma unroll
  for (int ks = 0; ks < 2; ++ks)
    qf[ks] = *reinterpret_cast<const bf16x8*>(qb + ks * 32 + ((lane >> 4) << 3));

  __syncthreads();

  // QK^T: logits [16 rows][256]
  f32x4 ln[16] = {};
#pragma unroll
  for (int ks = 0; ks < 2; ++ks) {
    const int slot = ks * 4 + (lane >> 4);
#pragma unroll
    for (int nf = 0; nf < 16; ++nf) {
      const int kcol = nf * 16 + (lane & 15);
      bf16x8 kf = *reinterpret_cast<const bf16x8*>(
          reinterpret_cast<const char*>(Ks) + kcol * 128 + ((slot ^ (kcol & 7)) << 4));
      ln[nf] = __builtin_amdgcn_mfma_f32_16x16x32_bf16(qf[ks], kf, ln[nf], 0, 0, 0);
    }
  }

  __syncthreads();  // all waves done reading Ks; Ps may now clobber it

#pragma unroll
  for (int r = 0; r < 4; ++r) {
    float m = -1e30f;
#pragma unroll
    for (int nf = 0; nf < 16; ++nf) m = fmaxf(m, ln[nf][r]);
#pragma unroll
    for (int s = 1; s < 16; s <<= 1) m = fmaxf(m, __shfl_xor(m, s, 64));
    float sum = 0.f;
#pragma unroll
    for (int nf = 0; nf < 16; ++nf) {
      float p = __expf((ln[nf][r] - m) * 0.125f);
      ln[nf][r] = p;
      sum += p;
    }
#pragma unroll
    for (int s = 1; s < 16; s <<= 1) sum += __shfl_xor(sum, s, 64);
    const float inv = 1.f / sum;
    const int row = ((lane >> 4) << 2) + r;
#pragma unroll
    for (int nf = 0; nf < 16; ++nf) {
      const int col = nf * 16 + (lane & 15);
      *reinterpret_cast<bf16*>(reinterpret_cast<char*>(Ps) + row * 512 +
                               ((col * 2) ^ ((row & 7) << 4))) = (bf16)(ln[nf][r] * inv);
    }
  }

  // PV: out[16][64] = P[16][256] @ V[256][64]
  f32x4 oacc[4] = {};
#pragma unroll
  for (int ks = 0; ks < 8; ++ks) {
    const int ak = ks * 32 + ((lane >> 4) << 3);
    const int arow = lane & 15;
    bf16x8 pa = *reinterpret_cast<const bf16x8*>(
        reinterpret_cast<const char*>(Ps) + arow * 512 + ((ak * 2) ^ ((arow & 7) << 4)));
#pragma unroll
    for (int nf = 0; nf < 4; ++nf) {
      const int d2 = nf * 16 + (lane & 15);
      const int swz = (((d2 & 7) ^ ((d2 >> 3) & 7)) << 4);
      bf16x8 vv = *reinterpret_cast<const bf16x8*>(
          reinterpret_cast<const char*>(Vs) + d2 * 512 + ((ak * 2) ^ swz));
      oacc[nf] = __builtin_amdgcn_mfma_f32_16x16x32_bf16(pa, vv, oacc[nf], 0, 0, 0);
    }
  }

  bf16* ob = aout + ((long)(b * 4096 + lt * 64 + wid * 16 + ((lane >> 4) << 2))) * 1024 +
             h * 64 + (lane & 15);
#pragma unroll
  for (int nf = 0; nf < 4; ++nf)
#pragma unroll
    for (int r = 0; r < 4; ++r) ob[(long)r * 1024 + nf * 16] = (bf16)oacc[nf][r];
}

// --------------------------------------------------------------------- launch
extern "C" void kernel_launch(void* const* d_in, const int* in_sizes, int n_in,
                              void* d_out, int out_size, void* d_ws, size_t ws_size,
                              hipStream_t stream) {
  const float* x  = (const float*)d_in[0];
  const float* Wq = (const float*)d_in[1];
  const float* Wk = (const float*)d_in[2];
  const float* Wv = (const float*)d_in[3];
  const float* Wo = (const float*)d_in[4];
  const float* Pk = (const float*)d_in[5];
  const float* Pv = (const float*)d_in[6];
  char* ws = (char*)d_ws;
  const long MB = 1024L * 1024;
  bf16* xbf = (bf16*)ws;               // 32 MB  (dead after Q gemm -> reused as aout)
  bf16* XT  = (bf16*)(ws + 32 * MB);   // 32 MB  x^T per batch [1024][4096]
  bf16* WqT = (bf16*)(ws + 64 * MB);   // 2 MB
  bf16* WkT = (bf16*)(ws + 66 * MB);
  bf16* WvT = (bf16*)(ws + 68 * MB);
  bf16* WoT = (bf16*)(ws + 70 * MB);
  bf16* PT  = (bf16*)(ws + 72 * MB);   // 4 MB  [Pk^T ; Pv^T] = [512][4096]
  float* XCp = (float*)(ws + 76 * MB); // 32 MB fp32 split-K partials (dead before qbf)
  bf16* qbf = (bf16*)(ws + 76 * MB);   // 32 MB (after reduce)
  bf16* XC  = (bf16*)(ws + 108 * MB);  // 4 MB  [4][512][1024]
  bf16* kvc = (bf16*)(ws + 112 * MB);  // 4 MB  [4][ kc(256) ; vc(256) ][1024]
  bf16* aout = xbf;
  const int BIG = 1 << 30;
  (void)in_sizes; (void)n_in; (void)out_size; (void)ws_size;

  // 1) x -> xbf (bf16) and XT (x^T per batch), one pass over x
  k_castT<<<dim3(16, 64, 4), 256, 0, stream>>>(x, xbf, XT);

  // 2) W transposes (bf16)
  TP4 tw = {{Wq, Wk, Wv, Wo}, {WqT, WkT, WvT, WoT}};
  k_tcast<<<dim3(16, 16, 4), 256, 0, stream>>>(tw, 1024, 1024);

  // 3) P transposes into PT cat
  TP4 tp = {{Pk, Pv, Pk, Pk}, {PT, PT + 256 * 4096, PT, PT}};
  k_tcast<<<dim3(4, 64, 2), 256, 0, stream>>>(tp, 4096, 256);

  // 4) XC partials: z = b*4 + kchunk, K-chunk = 1024   (512 blocks)
  k_gemm_nt<float><<<dim3(4, 8, 16), 256, 0, stream>>>(
      PT, XT, XT, XCp, 4096, 4096, 1024, 1024, 0, 1024L * 4096, 512L * 1024, 4, 1024,
      BIG);
  // 4b) reduce partials -> XC bf16
  k_red4<<<dim3(2048), 256, 0, stream>>>(XCp, XC);

  // 5) kvc[b] = [XCk@Wk ; XCv@Wv] block-diagonal (mb<2 -> Wk, else Wv)
  k_gemm_nt<bf16><<<dim3(4, 8, 4), 256, 0, stream>>>(
      XC, WkT, WvT, kvc, 1024, 1024, 1024, 1024, 512L * 1024, 0, 512L * 1024, 1, 0, 2);

  // 6) Q = x @ Wq   [16384,1024]  (XCp region now dead -> qbf)
  k_gemm_nt<bf16><<<dim3(128, 8, 1), 256, 0, stream>>>(
      xbf, WqT, WqT, qbf, 1024, 1024, 1024, 1024, 0, 0, 0, 1, 0, BIG);

  // 7) attention
  k_attn<<<dim3(64, 16, 4), 256, 0, stream>>>(qbf, kvc, aout);

  // 8) out = aout @ Wo  (fp32 out)
  k_gemm_nt<float><<<dim3(128, 8, 1), 256, 0, stream>>>(
      aout, WoT, WoT, (float*)d_out, 1024, 1024, 1024, 1024, 0, 0, 0, 1, 0, BIG);
}